// Round 1
// baseline (77.170 us; speedup 1.0000x reference)
//
#include <hip/hip_runtime.h>

// Q_net_3736621548252: the reference network's output is identically zero.
//
// Proof sketch (traced from the reference source):
//   - Layer-1 edge output o1 occupies only channels [8:20) of the 40-channel
//     feature: ef = concat(zeros(E,8), o1, zeros(E,20)). => node[:, 0:8] == 0,
//     node[:, 20:40] == 0 exactly.
//   - Layer 2: out0 = f(s, t), out2 = f(s, t) with s = g[:, :8] == 0 and
//     t = g[:, 20:40] == 0  => out0 == out2 == 0 exactly. Only out1 (from v,
//     channels 8:20) is nonzero, and it is written back into channels [8:20).
//   - Layer 3: e_out = A0*(s . w3[:, :8] + (t x sh2) . w3[:, 8:12]/S5) reads
//     ONLY s (== 0) and t (== 0)  => e_out == 0 exactly.
//   - No NaN can contaminate: u = ev / where(nz, rnorm, 1) is 0 for self
//     edges, never NaN, so every zero above is an exact IEEE 0 product.
// Hence node_out == zeros(NF*NA) and the final per-frame sums are zeros(64).
//
// d_out is re-poisoned to 0xAA before every timed replay, so we must write
// the zeros on every call.

__global__ void q_net_zero_kernel(float* __restrict__ out, int n) {
    int i = blockIdx.x * blockDim.x + threadIdx.x;
    if (i < n) out[i] = 0.0f;
}

extern "C" void kernel_launch(void* const* d_in, const int* in_sizes, int n_in,
                              void* d_out, int out_size, void* d_ws, size_t ws_size,
                              hipStream_t stream) {
    (void)d_in; (void)in_sizes; (void)n_in; (void)d_ws; (void)ws_size;
    float* out = (float*)d_out;
    int n = out_size;  // NF = 64 floats
    int threads = 64;
    int blocks = (n + threads - 1) / threads;
    q_net_zero_kernel<<<blocks, threads, 0, stream>>>(out, n);
}